// Round 1
// baseline (607.137 us; speedup 1.0000x reference)
//
#include <hip/hip_runtime.h>
#include <math.h>

// Problem constants (fixed by the reference)
#define BATCH     16384
#define EMBED     128
#define NUM_NEG   100
#define ROWS_PB   64                 // batch rows per block
#define NBLOCKS   (BATCH / ROWS_PB)  // 256
#define KG        4                  // k-groups (one wave each)
#define KPT       (NUM_NEG / KG)     // 25 negatives per thread
#define D4        (EMBED / 4)        // 32 float4 per row

__device__ __forceinline__ float softplus(float x) {
    // log(1 + exp(x)), numerically stable
    return fmaxf(x, 0.0f) + log1pf(expf(-fabsf(x)));
}

__global__ __launch_bounds__(256) void ke_main(
    const float* __restrict__ head_table,
    const float* __restrict__ tail_table,
    const float* __restrict__ relation_vec,
    const float* __restrict__ bias_table,
    const int*   __restrict__ head_idxs,
    const int*   __restrict__ tail_idxs,
    const int*   __restrict__ neg_idxs,
    float*       __restrict__ partials)
{
    // LDS: neg matrix 100x128 f32 = 50 KB, staged once per block.
    // All inner-loop reads are wave-uniform addresses -> broadcast (conflict-free).
    __shared__ float4 neg_lds[NUM_NEG * D4];
    __shared__ float4 rel_lds[D4];
    __shared__ float  wsum[KG];

    const int t = threadIdx.x;

    // Stage negatives: 100 rows x 32 float4 = 3200 float4, coalesced-ish gather
    for (int i = t; i < NUM_NEG * D4; i += 256) {
        const int k  = i >> 5;   // / D4
        const int d4 = i & 31;   // % D4
        const float4* src = (const float4*)(tail_table + (size_t)neg_idxs[k] * EMBED);
        neg_lds[i] = src[d4];
    }
    if (t < D4) rel_lds[t] = ((const float4*)relation_vec)[t];
    __syncthreads();

    const int r   = t & 63;   // row within tile (lane id)
    const int kg  = t >> 6;   // k-group == wave id (wave-uniform)
    const int row = blockIdx.x * ROWS_PB + r;

    const int   hidx = head_idxs[row];
    const int   tidx = tail_idxs[row];
    const float bias = bias_table[tidx];
    const float4* hrow = (const float4*)(head_table + (size_t)hidx * EMBED);
    const float4* trow = (const float4*)(tail_table + (size_t)tidx * EMBED);

    float acc[KPT];
    #pragma unroll
    for (int i = 0; i < KPT; ++i) acc[i] = 0.0f;
    float pos = 0.0f;

    const int kbase = kg * KPT;

    for (int d4 = 0; d4 < D4; ++d4) {
        const float4 h  = hrow[d4];
        const float4 rv = rel_lds[d4];                  // LDS broadcast
        const float4 e  = make_float4(h.x + rv.x, h.y + rv.y,
                                      h.z + rv.z, h.w + rv.w);
        if (kg == 0) {                                  // wave-uniform branch
            const float4 tv = trow[d4];
            pos = fmaf(e.x, tv.x, fmaf(e.y, tv.y, fmaf(e.z, tv.z, fmaf(e.w, tv.w, pos))));
        }
        #pragma unroll
        for (int kk = 0; kk < KPT; ++kk) {
            const float4 n = neg_lds[(kbase + kk) * D4 + d4];  // LDS broadcast
            acc[kk] = fmaf(e.x, n.x, fmaf(e.y, n.y, fmaf(e.z, n.z, fmaf(e.w, n.w, acc[kk]))));
        }
    }

    // Per-thread loss contribution
    float local = 0.0f;
    #pragma unroll
    for (int kk = 0; kk < KPT; ++kk)
        local += softplus(acc[kk] + bias);               // -log_sigmoid(-neg_logit)
    if (kg == 0)
        local += softplus(-(pos + bias));                // -log_sigmoid(pos_logit)

    // Block reduction: wave shuffle (64-wide) -> LDS -> wave 0
    #pragma unroll
    for (int off = 32; off; off >>= 1)
        local += __shfl_down(local, off, 64);
    if ((t & 63) == 0) wsum[kg] = local;
    __syncthreads();
    if (t == 0)
        partials[blockIdx.x] = wsum[0] + wsum[1] + wsum[2] + wsum[3];
}

__global__ __launch_bounds__(256) void ke_reduce(
    const float* __restrict__ partials, float* __restrict__ out)
{
    __shared__ float wsum[4];
    const int t = threadIdx.x;
    float v = partials[t];   // exactly NBLOCKS==256 partials
    #pragma unroll
    for (int off = 32; off; off >>= 1)
        v += __shfl_down(v, off, 64);
    if ((t & 63) == 0) wsum[t >> 6] = v;
    __syncthreads();
    if (t == 0)
        out[0] = (wsum[0] + wsum[1] + wsum[2] + wsum[3]) * (1.0f / (float)BATCH);
}

extern "C" void kernel_launch(void* const* d_in, const int* in_sizes, int n_in,
                              void* d_out, int out_size, void* d_ws, size_t ws_size,
                              hipStream_t stream)
{
    const float* head_table   = (const float*)d_in[0];
    const float* tail_table   = (const float*)d_in[1];
    const float* relation_vec = (const float*)d_in[2];
    const float* bias_table   = (const float*)d_in[3];
    const int*   head_idxs    = (const int*)d_in[4];
    const int*   tail_idxs    = (const int*)d_in[5];
    const int*   neg_idxs     = (const int*)d_in[6];
    float*       out          = (float*)d_out;
    float*       partials     = (float*)d_ws;   // NBLOCKS floats

    ke_main<<<NBLOCKS, 256, 0, stream>>>(head_table, tail_table, relation_vec,
                                         bias_table, head_idxs, tail_idxs,
                                         neg_idxs, partials);
    ke_reduce<<<1, 256, 0, stream>>>(partials, out);
}

// Round 2
// 587.610 us; speedup vs baseline: 1.0332x; 1.0332x over previous
//
#include <hip/hip_runtime.h>
#include <math.h>

// Problem constants (fixed by the reference)
#define BATCH     16384
#define EMBED     128
#define NUM_NEG   100
#define ROWS_PB   64                 // batch rows per block
#define NBLOCKS   (BATCH / ROWS_PB)  // 256
#define THREADS   512                // 8 waves
#define D4        (EMBED / 4)        // 32 float4 per row
#define KPT       13                 // waves 0..6: 13 negs; wave 7: 9 negs + pos
#define KPT_LAST  9                  // 7*13 + 9 = 100

__device__ __forceinline__ float softplus(float x) {
    // log(1 + exp(x)), numerically stable
    return fmaxf(x, 0.0f) + log1pf(expf(-fabsf(x)));
}

__device__ __forceinline__ float fma4(const float4 a, const float4 b, float c) {
    return fmaf(a.x, b.x, fmaf(a.y, b.y, fmaf(a.z, b.z, fmaf(a.w, b.w, c))));
}

__global__ __launch_bounds__(THREADS) void ke_main(
    const float* __restrict__ head_table,
    const float* __restrict__ tail_table,
    const float* __restrict__ relation_vec,
    const float* __restrict__ bias_table,
    const int*   __restrict__ head_idxs,
    const int*   __restrict__ tail_idxs,
    const int*   __restrict__ neg_idxs,
    float*       __restrict__ partials)
{
    // neg matrix 100x128 f32 = 50 KB; read wave-uniform -> broadcast, conflict-free
    __shared__ float4 neg_lds[NUM_NEG * D4];
    // e = head+rel, padded rows of 33 float4: lane-varying row reads spread
    // across bank-quads ((r*33+d4)%8 == (r%8+d4)%8) -> no 32-way conflict
    __shared__ float4 e_lds[ROWS_PB * 33];
    __shared__ float  wsum[8];

    const int t        = threadIdx.x;
    const int base_row = blockIdx.x * ROWS_PB;

    // ---- Stage negatives (3200 float4, 6-7 per thread) ----
    for (int i = t; i < NUM_NEG * D4; i += THREADS) {
        const int k  = i >> 5;
        const int d4 = i & 31;
        neg_lds[i] = ((const float4*)(tail_table + (size_t)neg_idxs[k] * EMBED))[d4];
    }
    // ---- Stage e = head_row + relation (2048 float4, 4 per thread) ----
    for (int i = t; i < ROWS_PB * D4; i += THREADS) {
        const int row = i >> 5;
        const int d4  = i & 31;
        const float4 h  = ((const float4*)(head_table +
                           (size_t)head_idxs[base_row + row] * EMBED))[d4];
        const float4 rv = ((const float4*)relation_vec)[d4];   // L1/L2-cached
        e_lds[row * 33 + d4] = make_float4(h.x + rv.x, h.y + rv.y,
                                           h.z + rv.z, h.w + rv.w);
    }
    __syncthreads();

    const int r   = t & 63;          // row within tile (lane id)
    const int kg  = t >> 6;          // wave id, 0..7 (wave-uniform)
    const int row = base_row + r;

    const int   tidx = tail_idxs[row];
    const float bias = bias_table[tidx];

    float acc[KPT];
    #pragma unroll
    for (int i = 0; i < KPT; ++i) acc[i] = 0.0f;
    float pos = 0.0f;

    float local = 0.0f;

    if (kg < 7) {                    // wave-uniform branch
        const int kbase = kg * KPT;
        #pragma unroll 4
        for (int d4 = 0; d4 < D4; ++d4) {
            const float4 e = e_lds[r * 33 + d4];
            #pragma unroll
            for (int kk = 0; kk < KPT; ++kk)
                acc[kk] = fma4(e, neg_lds[(kbase + kk) * D4 + d4], acc[kk]);
        }
        #pragma unroll
        for (int kk = 0; kk < KPT; ++kk)
            local += softplus(acc[kk] + bias);       // -log_sigmoid(-neg_logit)
    } else {                         // wave 7: 9 negs + positive dot
        const float4* trow = (const float4*)(tail_table + (size_t)tidx * EMBED);
        #pragma unroll 4
        for (int d4 = 0; d4 < D4; ++d4) {
            const float4 e  = e_lds[r * 33 + d4];
            pos = fma4(e, trow[d4], pos);
            #pragma unroll
            for (int kk = 0; kk < KPT_LAST; ++kk)
                acc[kk] = fma4(e, neg_lds[(91 + kk) * D4 + d4], acc[kk]);
        }
        #pragma unroll
        for (int kk = 0; kk < KPT_LAST; ++kk)
            local += softplus(acc[kk] + bias);
        local += softplus(-(pos + bias));            // -log_sigmoid(pos_logit)
    }

    // ---- Block reduction: wave shuffle (64-wide) -> LDS -> thread 0 ----
    #pragma unroll
    for (int off = 32; off; off >>= 1)
        local += __shfl_down(local, off, 64);
    if ((t & 63) == 0) wsum[kg] = local;
    __syncthreads();
    if (t == 0) {
        float s = 0.0f;
        #pragma unroll
        for (int w = 0; w < 8; ++w) s += wsum[w];
        partials[blockIdx.x] = s;
    }
}

__global__ __launch_bounds__(256) void ke_reduce(
    const float* __restrict__ partials, float* __restrict__ out)
{
    __shared__ float wsum[4];
    const int t = threadIdx.x;
    float v = partials[t];   // exactly NBLOCKS==256 partials
    #pragma unroll
    for (int off = 32; off; off >>= 1)
        v += __shfl_down(v, off, 64);
    if ((t & 63) == 0) wsum[t >> 6] = v;
    __syncthreads();
    if (t == 0)
        out[0] = (wsum[0] + wsum[1] + wsum[2] + wsum[3]) * (1.0f / (float)BATCH);
}

extern "C" void kernel_launch(void* const* d_in, const int* in_sizes, int n_in,
                              void* d_out, int out_size, void* d_ws, size_t ws_size,
                              hipStream_t stream)
{
    const float* head_table   = (const float*)d_in[0];
    const float* tail_table   = (const float*)d_in[1];
    const float* relation_vec = (const float*)d_in[2];
    const float* bias_table   = (const float*)d_in[3];
    const int*   head_idxs    = (const int*)d_in[4];
    const int*   tail_idxs    = (const int*)d_in[5];
    const int*   neg_idxs     = (const int*)d_in[6];
    float*       out          = (float*)d_out;
    float*       partials     = (float*)d_ws;   // NBLOCKS floats

    ke_main<<<NBLOCKS, THREADS, 0, stream>>>(head_table, tail_table, relation_vec,
                                             bias_table, head_idxs, tail_idxs,
                                             neg_idxs, partials);
    ke_reduce<<<1, 256, 0, stream>>>(partials, out);
}